// Round 1
// baseline (842.510 us; speedup 1.0000x reference)
//
#include <hip/hip_runtime.h>
#include <hip/hip_bf16.h>

#define N_ 2
#define L_ 512
#define RD_ 128
#define PD_ 64
#define H_ 12
#define QD_ 32
#define VD_ 32
#define QP_ 8
#define VP_ 8
#define NL_ (N_*L_)
#define QKV_ (H_*QD_)      /* 384 */
#define PTS_ (H_*QP_*3)    /* 288 */
#define FEAT_ 1824
#define INF_ 100000.0f

// ---------------------------------------------------------------------------
// K1: per-token projections.
//   q/k/v = residue @ W{q,k,v}.T   (384 each)
//   {q,k,v}p = R @ (residue @ W{q,k,v}p.T).reshape(96,3) + coord (global frame)
//   qq/kk = sum of squared global point coords per head
// ---------------------------------------------------------------------------
__global__ __launch_bounds__(256) void k_proj(
    const float* __restrict__ R, const float* __restrict__ coord,
    const float* __restrict__ resf,
    const float* __restrict__ Wq, const float* __restrict__ Wk, const float* __restrict__ Wv,
    const float* __restrict__ Wqp, const float* __restrict__ Wkp, const float* __restrict__ Wvp,
    float* __restrict__ q, float* __restrict__ k, float* __restrict__ v,
    float* __restrict__ qp, float* __restrict__ kp, float* __restrict__ vp,
    float* __restrict__ qq, float* __restrict__ kk)
{
  const int t = blockIdx.x;
  const int tid = threadIdx.x;
  __shared__ float rs[RD_];
  __shared__ float raw[3*PTS_];
  __shared__ float pg[2*PTS_];
  if (tid < RD_/4) ((float4*)rs)[tid] = ((const float4*)(resf + (size_t)t*RD_))[tid];
  __syncthreads();
  const float4* r4 = (const float4*)rs;

  for (int o = tid; o < 3*QKV_; o += 256) {
    int oo = o; const float* W; float* dst;
    if (oo < QKV_)        { W = Wq + (size_t)oo*RD_; dst = q; }
    else if (oo < 2*QKV_) { oo -= QKV_;  W = Wk + (size_t)oo*RD_; dst = k; }
    else                  { oo -= 2*QKV_; W = Wv + (size_t)oo*RD_; dst = v; }
    const float4* w4 = (const float4*)W;
    float acc = 0.f;
    #pragma unroll
    for (int c = 0; c < RD_/4; ++c) {
      float4 a = w4[c], b = r4[c];
      acc += a.x*b.x + a.y*b.y + a.z*b.z + a.w*b.w;
    }
    dst[(size_t)t*QKV_ + oo] = acc;
  }

  for (int o = tid; o < 3*PTS_; o += 256) {
    int oo = o; const float* W;
    if (oo < PTS_)        W = Wqp + (size_t)oo*RD_;
    else if (oo < 2*PTS_) W = Wkp + (size_t)(oo - PTS_)*RD_;
    else                  W = Wvp + (size_t)(oo - 2*PTS_)*RD_;
    const float4* w4 = (const float4*)W;
    float acc = 0.f;
    #pragma unroll
    for (int c = 0; c < RD_/4; ++c) {
      float4 a = w4[c], b = r4[c];
      acc += a.x*b.x + a.y*b.y + a.z*b.z + a.w*b.w;
    }
    raw[o] = acc;
  }
  __syncthreads();

  const float* Rm = R + (size_t)t*9;
  const float cx = coord[(size_t)t*3+0], cy = coord[(size_t)t*3+1], cz = coord[(size_t)t*3+2];
  for (int m = tid; m < 3*96; m += 256) {
    int mat = m / 96, mm = m % 96;
    const float* p = raw + mat*PTS_ + mm*3;
    float px = p[0], py = p[1], pz = p[2];
    float gx = Rm[0]*px + Rm[1]*py + Rm[2]*pz + cx;
    float gy = Rm[3]*px + Rm[4]*py + Rm[5]*pz + cy;
    float gz = Rm[6]*px + Rm[7]*py + Rm[8]*pz + cz;
    float* dst = (mat == 0 ? qp : mat == 1 ? kp : vp) + (size_t)t*PTS_ + mm*3;
    dst[0] = gx; dst[1] = gy; dst[2] = gz;
    if (mat < 2) { float* g = pg + mat*PTS_ + mm*3; g[0]=gx; g[1]=gy; g[2]=gz; }
  }
  __syncthreads();

  if (tid < 24) {
    int mat = tid / 12, h = tid % 12;
    const float* p = pg + mat*PTS_ + h*(QP_*3);
    float s = 0.f;
    #pragma unroll
    for (int c = 0; c < QP_*3; ++c) s += p[c]*p[c];
    (mat == 0 ? qq : kk)[(size_t)t*H_ + h] = s;
  }
}

// ---------------------------------------------------------------------------
// K2: attention, one block per (n,i). 256 threads.
//   Pass A: logits[j][h] -> LDS (node + pair-bias + spatial dist), masked
//   Pass B: per-head softmax (one wave per head, round-robin)
//   Pass C: feat_node / feat_pair / point aggregation + spatial features
// ---------------------------------------------------------------------------
__global__ __launch_bounds__(256) void k_attn(
    const float* __restrict__ pair, const int* __restrict__ mask,
    const float* __restrict__ Wpb, const float* __restrict__ spc,
    const float* __restrict__ R, const float* __restrict__ coord,
    const float* __restrict__ q, const float* __restrict__ k, const float* __restrict__ v,
    const float* __restrict__ qp, const float* __restrict__ kp, const float* __restrict__ vp,
    const float* __restrict__ qq, const float* __restrict__ kk,
    float* __restrict__ feat)
{
  const int bi = blockIdx.x;        // n*L + i
  const int n  = bi / L_;
  const int nL = n * L_;
  const int tid = threadIdx.x;

  __shared__ float qi[QKV_];
  __shared__ float qpi[PTS_];
  __shared__ float qqi[H_];
  __shared__ float wpb[H_*PD_];
  __shared__ float coefh[H_];
  __shared__ float lg[L_*H_];       // 24 KB: logits then alpha
  __shared__ float aggrS[H_*VP_*3];

  for (int o = tid; o < QKV_;   o += 256) qi[o]  = q[(size_t)bi*QKV_ + o];
  for (int o = tid; o < PTS_;   o += 256) qpi[o] = qp[(size_t)bi*PTS_ + o];
  for (int o = tid; o < H_*PD_; o += 256) wpb[o] = Wpb[o];
  if (tid < H_) {
    qqi[tid]   = qq[(size_t)bi*H_ + tid];
    // -softplus(c) * sqrt(2/(9*QP))/2 = -softplus(c)/12
    coefh[tid] = -log1pf(expf(spc[tid])) * (1.0f/12.0f);
  }
  __syncthreads();

  const int mi = mask[bi];
  const float inv_sqrt_qd = 0.17677669529663687f;  // 1/sqrt(32)
  const float inv_sqrt3   = 0.5773502691896258f;   // sqrt(1/3)

  // ---- Pass A: logits ----
  for (int j = tid; j < L_; j += 256) {
    const float4* kr  = (const float4*)(k  + (size_t)(nL + j)*QKV_);
    const float4* kpr = (const float4*)(kp + (size_t)(nL + j)*PTS_);
    const float*  kkr = kk + (size_t)(nL + j)*H_;
    const float4* pr  = (const float4*)(pair + ((size_t)bi*L_ + j)*PD_);
    float4 pv[PD_/4];
    #pragma unroll
    for (int c = 0; c < PD_/4; ++c) pv[c] = pr[c];
    const float mterm = (mi && mask[nL + j]) ? 0.f : -INF_;
    #pragma unroll 2
    for (int h = 0; h < H_; ++h) {
      float nd = 0.f;
      #pragma unroll
      for (int c = 0; c < QD_/4; ++c) {
        float4 a = kr[h*(QD_/4) + c];
        nd += a.x*qi[h*QD_+4*c] + a.y*qi[h*QD_+4*c+1] + a.z*qi[h*QD_+4*c+2] + a.w*qi[h*QD_+4*c+3];
      }
      float pd = 0.f;
      #pragma unroll
      for (int c = 0; c < 6; ++c) {
        float4 a = kpr[h*6 + c];
        pd += a.x*qpi[h*24+4*c] + a.y*qpi[h*24+4*c+1] + a.z*qpi[h*24+4*c+2] + a.w*qpi[h*24+4*c+3];
      }
      float pl = 0.f;
      #pragma unroll
      for (int c = 0; c < PD_/4; ++c) {
        float4 b = pv[c];
        pl += b.x*wpb[h*PD_+4*c] + b.y*wpb[h*PD_+4*c+1] + b.z*wpb[h*PD_+4*c+2] + b.w*wpb[h*PD_+4*c+3];
      }
      float ss = qqi[h] + kkr[h] - 2.f*pd;
      lg[j*H_ + h] = (nd*inv_sqrt_qd + pl + ss*coefh[h]) * inv_sqrt3 + mterm;
    }
  }
  __syncthreads();

  // ---- Pass B: softmax over j per head; one wave per head (rr) ----
  {
    const int wid = tid >> 6, lane = tid & 63;
    for (int h = wid; h < H_; h += 4) {
      float m = -1e30f;
      for (int j = lane; j < L_; j += 64) m = fmaxf(m, lg[j*H_ + h]);
      #pragma unroll
      for (int off = 1; off < 64; off <<= 1) m = fmaxf(m, __shfl_xor(m, off, 64));
      float s = 0.f;
      for (int j = lane; j < L_; j += 64) s += expf(lg[j*H_ + h] - m);
      #pragma unroll
      for (int off = 1; off < 64; off <<= 1) s += __shfl_xor(s, off, 64);
      const float inv = (mi ? 1.f : 0.f) / s;  // alpha zeroed when query masked
      for (int j = lane; j < L_; j += 64) lg[j*H_ + h] = expf(lg[j*H_ + h] - m) * inv;
    }
  }
  __syncthreads();

  // ---- Pass C: weighted sums. 1440 outputs: node 384 | pair 768 | aggr 288 ----
  float* fb = feat + (size_t)bi*FEAT_;
  for (int o = tid; o < 1440; o += 256) {
    const float* src; int stride; int h;
    if (o < 384)       { h = o >> 5;  src = v + (size_t)nL*QKV_ + o; stride = QKV_; }
    else if (o < 1152) { int oo = o - 384;  h = oo >> 6; src = pair + ((size_t)bi*L_)*PD_ + (oo & 63); stride = PD_; }
    else               { int oo = o - 1152; h = oo / 24; src = vp + (size_t)nL*PTS_ + oo; stride = PTS_; }
    float acc = 0.f;
    #pragma unroll 4
    for (int j = 0; j < L_; ++j) acc += lg[j*H_ + h] * src[(size_t)j*stride];
    // feat_all layout: [pair 0..767 | node 768..1151 | points 1152..1439 | dist 1440..1535 | dir 1536..1823]
    if (o < 384)       fb[768 + o] = acc;
    else if (o < 1152) fb[o - 384] = acc;
    else               aggrS[o - 1152] = acc;
  }
  __syncthreads();

  // ---- spatial post-process: local frame, dist, dir ----
  const float* Rm = R + (size_t)bi*9;
  const float cx = coord[(size_t)bi*3+0], cy = coord[(size_t)bi*3+1], cz = coord[(size_t)bi*3+2];
  for (int m = tid; m < 96; m += 256) {
    float dx = aggrS[m*3+0] - cx, dy = aggrS[m*3+1] - cy, dz = aggrS[m*3+2] - cz;
    // R^T @ diff  (einsum 'nlji,nlhpj->nlhpi')
    float fx = Rm[0]*dx + Rm[3]*dy + Rm[6]*dz;
    float fy = Rm[1]*dx + Rm[4]*dy + Rm[7]*dz;
    float fz = Rm[2]*dx + Rm[5]*dy + Rm[8]*dz;
    float dist = sqrtf(fx*fx + fy*fy + fz*fz);
    float idn = 1.f / (dist + 1e-4f);
    fb[1152 + m*3+0] = fx; fb[1152 + m*3+1] = fy; fb[1152 + m*3+2] = fz;
    fb[1440 + m] = dist;
    fb[1536 + m*3+0] = fx*idn; fb[1536 + m*3+1] = fy*idn; fb[1536 + m*3+2] = fz*idn;
  }
}

// ---------------------------------------------------------------------------
// K3: block per token, 128 threads (thread = output feature).
//   out = LN2( x + MLP(x) ),  x = LN1(residue + mask*(feat@Wout.T + bout))
// ---------------------------------------------------------------------------
__device__ __forceinline__ float bsum128(float v, float* red, int tid) {
  #pragma unroll
  for (int off = 1; off < 64; off <<= 1) v += __shfl_xor(v, off, 64);
  __syncthreads();
  if ((tid & 63) == 0) red[tid >> 6] = v;
  __syncthreads();
  return red[0] + red[1];
}

__global__ __launch_bounds__(128) void k_out(
    const float* __restrict__ resf, const int* __restrict__ mask,
    const float* __restrict__ feat,
    const float* __restrict__ Wout, const float* __restrict__ bout,
    const float* __restrict__ Wm1, const float* __restrict__ bm1,
    const float* __restrict__ Wm2, const float* __restrict__ bm2,
    const float* __restrict__ Wm3, const float* __restrict__ bm3,
    const float* __restrict__ g1, const float* __restrict__ b1,
    const float* __restrict__ g2, const float* __restrict__ b2,
    float* __restrict__ out)
{
  const int t = blockIdx.x, tid = threadIdx.x;
  __shared__ float fr[FEAT_];
  __shared__ float xb[RD_], h1b[RD_], h2b[RD_];
  __shared__ float red[2];
  for (int o = tid; o < FEAT_; o += 128) fr[o] = feat[(size_t)t*FEAT_ + o];
  __syncthreads();

  float acc = bout[tid];
  {
    const float4* w4 = (const float4*)(Wout + (size_t)tid*FEAT_);
    #pragma unroll 4
    for (int c = 0; c < FEAT_/4; ++c) {
      float4 a = w4[c];
      acc += a.x*fr[4*c] + a.y*fr[4*c+1] + a.z*fr[4*c+2] + a.w*fr[4*c+3];
    }
  }
  if (mask[t] == 0) acc = 0.f;
  float r = resf[(size_t)t*RD_ + tid] + acc;

  float mean = bsum128(r, red, tid) * (1.f/RD_);
  float d = r - mean;
  float var = bsum128(d*d, red, tid) * (1.f/RD_);
  float xn = d * rsqrtf(var + 1e-5f) * g1[tid] + b1[tid];
  xb[tid] = xn;
  __syncthreads();

  float a1 = bm1[tid];
  {
    const float4* w4 = (const float4*)(Wm1 + (size_t)tid*RD_);
    #pragma unroll
    for (int c = 0; c < RD_/4; ++c) { float4 a = w4[c]; a1 += a.x*xb[4*c]+a.y*xb[4*c+1]+a.z*xb[4*c+2]+a.w*xb[4*c+3]; }
  }
  a1 = fmaxf(a1, 0.f);
  h1b[tid] = a1;
  __syncthreads();

  float a2 = bm2[tid];
  {
    const float4* w4 = (const float4*)(Wm2 + (size_t)tid*RD_);
    #pragma unroll
    for (int c = 0; c < RD_/4; ++c) { float4 a = w4[c]; a2 += a.x*h1b[4*c]+a.y*h1b[4*c+1]+a.z*h1b[4*c+2]+a.w*h1b[4*c+3]; }
  }
  a2 = fmaxf(a2, 0.f);
  h2b[tid] = a2;
  __syncthreads();

  float a3 = bm3[tid];
  {
    const float4* w4 = (const float4*)(Wm3 + (size_t)tid*RD_);
    #pragma unroll
    for (int c = 0; c < RD_/4; ++c) { float4 a = w4[c]; a3 += a.x*h2b[4*c]+a.y*h2b[4*c+1]+a.z*h2b[4*c+2]+a.w*h2b[4*c+3]; }
  }
  float r2 = xn + a3;
  float mean2 = bsum128(r2, red, tid) * (1.f/RD_);
  float d2 = r2 - mean2;
  float var2 = bsum128(d2*d2, red, tid) * (1.f/RD_);
  out[(size_t)t*RD_ + tid] = d2 * rsqrtf(var2 + 1e-5f) * g2[tid] + b2[tid];
}

// ---------------------------------------------------------------------------
extern "C" void kernel_launch(void* const* d_in, const int* in_sizes, int n_in,
                              void* d_out, int out_size, void* d_ws, size_t ws_size,
                              hipStream_t stream) {
  const float* R     = (const float*)d_in[0];
  const float* coord = (const float*)d_in[1];
  const float* resf  = (const float*)d_in[2];
  const float* pair  = (const float*)d_in[3];
  const int*   mask  = (const int*)  d_in[4];
  const float* Wq    = (const float*)d_in[5];
  const float* Wk    = (const float*)d_in[6];
  const float* Wv    = (const float*)d_in[7];
  const float* Wpb   = (const float*)d_in[8];
  const float* spc   = (const float*)d_in[9];
  const float* Wqp   = (const float*)d_in[10];
  const float* Wkp   = (const float*)d_in[11];
  const float* Wvp   = (const float*)d_in[12];
  const float* Wout  = (const float*)d_in[13];
  const float* bout  = (const float*)d_in[14];
  const float* Wm1   = (const float*)d_in[15];
  const float* bm1   = (const float*)d_in[16];
  const float* Wm2   = (const float*)d_in[17];
  const float* bm2   = (const float*)d_in[18];
  const float* Wm3   = (const float*)d_in[19];
  const float* bm3   = (const float*)d_in[20];
  const float* g1    = (const float*)d_in[21];
  const float* b1    = (const float*)d_in[22];
  const float* g2    = (const float*)d_in[23];
  const float* b2    = (const float*)d_in[24];

  float* ws = (float*)d_ws;
  float* q    = ws;                       // NL*384
  float* k    = q    + (size_t)NL_*QKV_;  // NL*384
  float* v    = k    + (size_t)NL_*QKV_;  // NL*384
  float* qp   = v    + (size_t)NL_*QKV_;  // NL*288
  float* kp   = qp   + (size_t)NL_*PTS_;  // NL*288
  float* vp   = kp   + (size_t)NL_*PTS_;  // NL*288
  float* qq   = vp   + (size_t)NL_*PTS_;  // NL*12
  float* kk   = qq   + (size_t)NL_*H_;    // NL*12
  float* feat = kk   + (size_t)NL_*H_;    // NL*1824  (~15.8 MB total)

  k_proj<<<NL_, 256, 0, stream>>>(R, coord, resf, Wq, Wk, Wv, Wqp, Wkp, Wvp,
                                  q, k, v, qp, kp, vp, qq, kk);
  k_attn<<<NL_, 256, 0, stream>>>(pair, mask, Wpb, spc, R, coord,
                                  q, k, v, qp, kp, vp, qq, kk, feat);
  k_out<<<NL_, 128, 0, stream>>>(resf, mask, feat, Wout, bout,
                                 Wm1, bm1, Wm2, bm2, Wm3, bm3,
                                 g1, b1, g2, b2, (float*)d_out);
}

// Round 2
// 317.596 us; speedup vs baseline: 2.6528x; 2.6528x over previous
//
#include <hip/hip_runtime.h>
#include <hip/hip_bf16.h>

#define N_ 2
#define L_ 512
#define RD_ 128
#define PD_ 64
#define H_ 12
#define NL_ (N_*L_)
#define POUT_ 2016          /* 3*384 + 3*288 */
#define FEAT_ 1824
#define INF_ 100000.0f
#define ISQD_ 0.17677669529663687f   /* 1/sqrt(32) */
#define ISQ3_ 0.5773502691896258f    /* sqrt(1/3) */

// ---------------------------------------------------------------------------
// K1: projection GEMM. proj[token][2016] = resf @ [Wq|Wk|Wv|Wqp|Wkp|Wvp]^T
// block: 8 tokens x 128 outputs, K=128 in one LDS tile.
// ---------------------------------------------------------------------------
__global__ __launch_bounds__(256) void k_proj_gemm(
    const float* __restrict__ resf,
    const float* __restrict__ Wq, const float* __restrict__ Wk, const float* __restrict__ Wv,
    const float* __restrict__ Wqp, const float* __restrict__ Wkp, const float* __restrict__ Wvp,
    float* __restrict__ proj)
{
  const int rb = blockIdx.x * 8;
  const int ob = blockIdx.y * 128;
  const int tid = threadIdx.x;
  __shared__ float xt[8*132];
  __shared__ float wt[128*132];
  {
    int r = tid >> 5, kq = (tid & 31) * 4;
    float4 v = *(const float4*)(resf + (size_t)(rb + r)*RD_ + kq);
    xt[r*132+kq]=v.x; xt[r*132+kq+1]=v.y; xt[r*132+kq+2]=v.z; xt[r*132+kq+3]=v.w;
  }
  for (int m = 0; m < 16; ++m) {
    int idx = m*256 + tid;
    int r = idx >> 5, kq = (idx & 31) * 4;
    int o = ob + r;
    float4 v;
    if (o < 384)        v = *(const float4*)(Wq  + (size_t)o*RD_ + kq);
    else if (o < 768)   v = *(const float4*)(Wk  + (size_t)(o-384)*RD_ + kq);
    else if (o < 1152)  v = *(const float4*)(Wv  + (size_t)(o-768)*RD_ + kq);
    else if (o < 1440)  v = *(const float4*)(Wqp + (size_t)(o-1152)*RD_ + kq);
    else if (o < 1728)  v = *(const float4*)(Wkp + (size_t)(o-1440)*RD_ + kq);
    else if (o < POUT_) v = *(const float4*)(Wvp + (size_t)(o-1728)*RD_ + kq);
    else                v = make_float4(0.f,0.f,0.f,0.f);
    wt[r*132+kq]=v.x; wt[r*132+kq+1]=v.y; wt[r*132+kq+2]=v.z; wt[r*132+kq+3]=v.w;
  }
  __syncthreads();
  const int tt = tid & 7, g = tid >> 3;
  float acc0=0.f, acc1=0.f, acc2=0.f, acc3=0.f;
  #pragma unroll 4
  for (int k2 = 0; k2 < RD_; ++k2) {
    float xv = xt[tt*132 + k2];
    acc0 += xv * wt[(g     )*132 + k2];
    acc1 += xv * wt[(g + 32)*132 + k2];
    acc2 += xv * wt[(g + 64)*132 + k2];
    acc3 += xv * wt[(g + 96)*132 + k2];
  }
  float* dst = proj + (size_t)(rb + tt)*POUT_ + ob;
  if (ob + g      < POUT_) dst[g]      = acc0;
  if (ob + g + 32 < POUT_) dst[g+32]   = acc1;
  if (ob + g + 64 < POUT_) dst[g+64]   = acc2;
  if (ob + g + 96 < POUT_) dst[g+96]   = acc3;
}

// ---------------------------------------------------------------------------
// K2: per-token rotate + build Q~/K~ (58-dim augmented vectors, padded to 64)
//   Qt[n][h][i][64] = [ q/sqrt(32) | -2*coef_h*qp_g | coef_h*qq | coef_h | 0.. ]
//   Kt[n][h][j][64] = [ k          | kp_g           | 1         | kk     | 0.. ]
//   vpg[token][288] = global-frame v-points
// ---------------------------------------------------------------------------
__global__ __launch_bounds__(64) void k_rot(
    const float* __restrict__ R, const float* __restrict__ coord,
    const float* __restrict__ spc, const float* __restrict__ proj,
    float* __restrict__ qt, float* __restrict__ kt, float* __restrict__ vpg)
{
  const int t = blockIdx.x;
  const int n = t / L_, i = t % L_;
  const int tid = threadIdx.x;
  __shared__ float prow[POUT_];
  __shared__ float qpl[288], kpl[288], vpl[288];
  __shared__ float qqs[H_], kks[H_], coefs[H_];
  for (int m = tid; m < POUT_/4; m += 64)
    ((float4*)prow)[m] = *((const float4*)(proj + (size_t)t*POUT_) + m);
  if (tid < H_) coefs[tid] = -log1pf(expf(spc[tid])) * (1.0f/12.0f);
  __syncthreads();
  const float* Rm = R + (size_t)t*9;
  const float r00=Rm[0],r01=Rm[1],r02=Rm[2],r10=Rm[3],r11=Rm[4],r12=Rm[5],r20=Rm[6],r21=Rm[7],r22=Rm[8];
  const float cx = coord[(size_t)t*3], cy = coord[(size_t)t*3+1], cz = coord[(size_t)t*3+2];
  for (int idx = tid; idx < 288; idx += 64) {
    int mat = idx / 96, p = idx % 96;
    const float* s = prow + 1152 + mat*288 + p*3;
    float px=s[0], py=s[1], pz=s[2];
    float gx = r00*px + r01*py + r02*pz + cx;
    float gy = r10*px + r11*py + r12*pz + cy;
    float gz = r20*px + r21*py + r22*pz + cz;
    float* d = (mat==0? qpl : mat==1? kpl : vpl) + p*3;
    d[0]=gx; d[1]=gy; d[2]=gz;
  }
  __syncthreads();
  if (tid < 24) {
    int mat = tid / H_, h = tid % H_;
    const float* s = (mat==0? qpl : kpl) + h*24;
    float acc = 0.f;
    #pragma unroll
    for (int c2 = 0; c2 < 24; ++c2) acc += s[c2]*s[c2];
    (mat==0? qqs : kks)[h] = acc;
  }
  for (int m = tid; m < 72; m += 64)
    ((float4*)(vpg + (size_t)t*288))[m] = ((float4*)vpl)[m];
  __syncthreads();
  for (int idx = tid; idx < 2*H_*64; idx += 64) {
    int which = idx / 768, rem = idx % 768, h = rem >> 6, c = rem & 63;
    float val;
    if (which == 0) {
      if (c < 32)       val = prow[h*32 + c] * ISQD_;
      else if (c < 56)  val = qpl[h*24 + (c-32)] * (-2.0f * coefs[h]);
      else if (c == 56) val = coefs[h] * qqs[h];
      else if (c == 57) val = coefs[h];
      else              val = 0.f;
      qt[((size_t)(n*H_ + h)*L_ + i)*64 + c] = val;
    } else {
      if (c < 32)       val = prow[384 + h*32 + c];
      else if (c < 56)  val = kpl[h*24 + (c-32)];
      else if (c == 56) val = 1.0f;
      else if (c == 57) val = kks[h];
      else              val = 0.f;
      kt[((size_t)(n*H_ + h)*L_ + i)*64 + c] = val;
    }
  }
}

// ---------------------------------------------------------------------------
// K3: logits GEMM (node+spatial): lgal[n][h][i][j] = Qt[i] . Kt[j]
// block: (j-tile 64, i-tile 64, n*H+h); classic 4x4 micro-tile per thread.
// ---------------------------------------------------------------------------
__global__ __launch_bounds__(256) void k_lgns(
    const float* __restrict__ qt, const float* __restrict__ kt,
    float* __restrict__ lgal)
{
  const int jb = blockIdx.x * 64, ib = blockIdx.y * 64, nh = blockIdx.z;
  const int tid = threadIdx.x;
  __shared__ float qs[64*65], ks[64*65];
  for (int m = 0; m < 4; ++m) {
    int idx = m*256 + tid;
    int r = idx >> 4, kq = (idx & 15) * 4;
    float4 a = *(const float4*)(qt + ((size_t)nh*L_ + ib + r)*64 + kq);
    qs[r*65+kq]=a.x; qs[r*65+kq+1]=a.y; qs[r*65+kq+2]=a.z; qs[r*65+kq+3]=a.w;
    float4 b = *(const float4*)(kt + ((size_t)nh*L_ + jb + r)*64 + kq);
    ks[r*65+kq]=b.x; ks[r*65+kq+1]=b.y; ks[r*65+kq+2]=b.z; ks[r*65+kq+3]=b.w;
  }
  __syncthreads();
  const int tx = tid & 15, ty = tid >> 4;
  const int i0 = ty*4, j0 = tx*4;
  float acc[4][4] = {};
  #pragma unroll 2
  for (int k2 = 0; k2 < 64; ++k2) {
    float qv[4], kv[4];
    #pragma unroll
    for (int d = 0; d < 4; ++d) { qv[d] = qs[(i0+d)*65 + k2]; kv[d] = ks[(j0+d)*65 + k2]; }
    #pragma unroll
    for (int a2 = 0; a2 < 4; ++a2)
      #pragma unroll
      for (int b2 = 0; b2 < 4; ++b2) acc[a2][b2] += qv[a2]*kv[b2];
  }
  #pragma unroll
  for (int a2 = 0; a2 < 4; ++a2) {
    float4 v = make_float4(acc[a2][0], acc[a2][1], acc[a2][2], acc[a2][3]);
    *(float4*)(lgal + ((size_t)nh*L_ + ib + i0 + a2)*L_ + jb + j0) = v;
  }
}

// ---------------------------------------------------------------------------
// K4: per (n,i): add pair-bias (streamed through LDS), mask, softmax -> alpha
// (in-place over lgal rows).
// ---------------------------------------------------------------------------
__global__ __launch_bounds__(256) void k_soft(
    const float* __restrict__ pair, const int* __restrict__ mask,
    const float* __restrict__ Wpb, float* __restrict__ lgal)
{
  const int bi = blockIdx.x, n = bi / L_, i = bi % L_, nL = n*L_;
  const int tid = threadIdx.x;
  __shared__ float lg[H_*512];
  __shared__ float pt[64*65];
  __shared__ float wpbl[H_*64];
  __shared__ float mterm[512];
  for (int m = 0; m < 6; ++m) {
    int idx = m*256 + tid;               // 1536 quads = 12 x 512
    int h = idx >> 7, jq = (idx & 127) * 4;
    *(float4*)(lg + h*512 + jq) =
        *(const float4*)(lgal + ((size_t)(n*H_+h)*L_ + i)*L_ + jq);
  }
  for (int m = tid; m < H_*16; m += 256) ((float4*)wpbl)[m] = ((const float4*)Wpb)[m];
  const int mi = mask[bi];
  for (int m = tid; m < 512; m += 256) mterm[m] = (mi && mask[nL + m]) ? 0.f : -INF_;
  __syncthreads();
  for (int jb2 = 0; jb2 < 512; jb2 += 64) {
    for (int m = 0; m < 4; ++m) {
      int idx = m*256 + tid;
      int r = idx >> 4, cq = (idx & 15) * 4;
      float4 v = *(const float4*)(pair + ((size_t)bi*L_ + jb2 + r)*PD_ + cq);
      pt[r*65+cq]=v.x; pt[r*65+cq+1]=v.y; pt[r*65+cq+2]=v.z; pt[r*65+cq+3]=v.w;
    }
    __syncthreads();
    for (int it = 0; it < 3; ++it) {
      int idx = it*256 + tid;            // 768 = 64 j x 12 h
      int jj = idx & 63, h = idx >> 6;
      float pl = 0.f;
      #pragma unroll 8
      for (int c2 = 0; c2 < PD_; ++c2) pl += pt[jj*65 + c2] * wpbl[h*64 + c2];
      int j = jb2 + jj;
      lg[h*512 + j] = (lg[h*512 + j] + pl) * ISQ3_ + mterm[j];
    }
    __syncthreads();
  }
  {
    const int wid = tid >> 6, lane = tid & 63;
    for (int h = wid; h < H_; h += 4) {
      float mx = -1e30f;
      for (int j = lane; j < 512; j += 64) mx = fmaxf(mx, lg[h*512+j]);
      #pragma unroll
      for (int off = 1; off < 64; off <<= 1) mx = fmaxf(mx, __shfl_xor(mx, off, 64));
      float s = 0.f;
      for (int j = lane; j < 512; j += 64) s += expf(lg[h*512+j]-mx);
      #pragma unroll
      for (int off = 1; off < 64; off <<= 1) s += __shfl_xor(s, off, 64);
      float inv = (mi ? 1.f : 0.f) / s;
      for (int j = lane; j < 512; j += 64) lg[h*512+j] = expf(lg[h*512+j]-mx) * inv;
    }
  }
  __syncthreads();
  for (int m = 0; m < 6; ++m) {
    int idx = m*256 + tid;
    int h = idx >> 7, jq = (idx & 127) * 4;
    *(float4*)(lgal + ((size_t)(n*H_+h)*L_ + i)*L_ + jq) = *(float4*)(lg + h*512 + jq);
  }
}

// ---------------------------------------------------------------------------
// K5: per (n,i): weighted aggregation. thread = (h, c-quad); alpha broadcast
// from LDS, all global loads coalesced float4.
// ---------------------------------------------------------------------------
__global__ __launch_bounds__(384) void k_aggr(
    const float* __restrict__ pair, const float* __restrict__ proj,
    const float* __restrict__ vpg, const float* __restrict__ lgal,
    const float* __restrict__ R, const float* __restrict__ coord,
    float* __restrict__ feat)
{
  const int bi = blockIdx.x, n = bi / L_, i = bi % L_, nL = n*L_;
  const int tid = threadIdx.x;
  __shared__ float al[H_*520];
  __shared__ float ag[288];
  for (int m = tid; m < H_*128; m += 384) {
    int h = m >> 7, jq = (m & 127) * 4;
    *(float4*)(al + h*520 + jq) =
        *(const float4*)(lgal + ((size_t)(n*H_+h)*L_ + i)*L_ + jq);
  }
  __syncthreads();
  float* fb = feat + (size_t)bi*FEAT_;
  if (tid < 360) {
    int h; const float* src; int stride;
    float4 acc = make_float4(0.f,0.f,0.f,0.f);
    if (tid < 192)      { h = tid >> 4; src = pair + ((size_t)bi*L_)*PD_ + (tid & 15)*4; stride = PD_; }
    else if (tid < 288) { int u = tid-192; h = u >> 3; src = proj + (size_t)nL*POUT_ + 768 + h*32 + (u&7)*4; stride = POUT_; }
    else                { int u = tid-288; h = u / 6;  src = vpg + (size_t)nL*288 + h*24 + (u%6)*4; stride = 288; }
    const float* arow = al + h*520;
    #pragma unroll 4
    for (int j = 0; j < 512; ++j) {
      float a = arow[j];
      float4 v = *(const float4*)(src + (size_t)j*stride);
      acc.x += a*v.x; acc.y += a*v.y; acc.z += a*v.z; acc.w += a*v.w;
    }
    if (tid < 192)      *(float4*)(fb + h*64 + (tid&15)*4) = acc;
    else if (tid < 288) { int u = tid-192; *(float4*)(fb + 768 + h*32 + (u&7)*4) = acc; }
    else                { int u = tid-288; *(float4*)(ag + h*24 + (u%6)*4) = acc; }
  }
  __syncthreads();
  const float* Rm = R + (size_t)bi*9;
  const float cx = coord[(size_t)bi*3], cy = coord[(size_t)bi*3+1], cz = coord[(size_t)bi*3+2];
  for (int m2 = tid; m2 < 96; m2 += 384) {
    float dx = ag[m2*3] - cx, dy = ag[m2*3+1] - cy, dz = ag[m2*3+2] - cz;
    float fx = Rm[0]*dx + Rm[3]*dy + Rm[6]*dz;
    float fy = Rm[1]*dx + Rm[4]*dy + Rm[7]*dz;
    float fz = Rm[2]*dx + Rm[5]*dy + Rm[8]*dz;
    float dist = sqrtf(fx*fx + fy*fy + fz*fz);
    float idn = 1.f/(dist + 1e-4f);
    fb[1152+m2*3]=fx; fb[1152+m2*3+1]=fy; fb[1152+m2*3+2]=fz;
    fb[1440+m2]=dist;
    fb[1536+m2*3]=fx*idn; fb[1536+m2*3+1]=fy*idn; fb[1536+m2*3+2]=fz*idn;
  }
}

// ---------------------------------------------------------------------------
// K6: y = feat @ Wout^T  (raw; bias/mask/resf applied in k_mlp)
// block: 4 tokens x 128 outputs; K-loop KC=96 (19 iters).
// ---------------------------------------------------------------------------
__global__ __launch_bounds__(256) void k_y_gemm(
    const float* __restrict__ feat, const float* __restrict__ Wout,
    float* __restrict__ ybuf)
{
  const int rb = blockIdx.x * 4;
  const int tid = threadIdx.x;
  __shared__ float wt[128*100];
  __shared__ float ft[4*100];
  const int tt = tid & 3, g = tid >> 2;
  float acc0 = 0.f, acc1 = 0.f;
  for (int kb = 0; kb < FEAT_; kb += 96) {
    for (int m = 0; m < 12; ++m) {
      int idx = m*256 + tid;
      int r = idx / 24, kq = (idx % 24) * 4;
      float4 v = *(const float4*)(Wout + (size_t)r*FEAT_ + kb + kq);
      wt[r*100+kq]=v.x; wt[r*100+kq+1]=v.y; wt[r*100+kq+2]=v.z; wt[r*100+kq+3]=v.w;
    }
    if (tid < 96) {
      int r = tid / 24, kq = (tid % 24) * 4;
      float4 v = *(const float4*)(feat + (size_t)(rb + r)*FEAT_ + kb + kq);
      ft[r*100+kq]=v.x; ft[r*100+kq+1]=v.y; ft[r*100+kq+2]=v.z; ft[r*100+kq+3]=v.w;
    }
    __syncthreads();
    #pragma unroll 4
    for (int k2 = 0; k2 < 96; ++k2) {
      float fv = ft[tt*100 + k2];
      acc0 += fv * wt[(g     )*100 + k2];
      acc1 += fv * wt[(g + 64)*100 + k2];
    }
    __syncthreads();
  }
  ybuf[(size_t)(rb+tt)*RD_ + g]      = acc0;
  ybuf[(size_t)(rb+tt)*RD_ + g + 64] = acc1;
}

// ---------------------------------------------------------------------------
// K7: per token: bias/mask/residual + LN1 + MLP + LN2
// ---------------------------------------------------------------------------
__device__ __forceinline__ float bsum128(float v, float* red, int tid) {
  #pragma unroll
  for (int off = 1; off < 64; off <<= 1) v += __shfl_xor(v, off, 64);
  __syncthreads();
  if ((tid & 63) == 0) red[tid >> 6] = v;
  __syncthreads();
  return red[0] + red[1];
}

__global__ __launch_bounds__(128) void k_mlp(
    const float* __restrict__ resf, const int* __restrict__ mask,
    const float* __restrict__ ybuf, const float* __restrict__ bout,
    const float* __restrict__ Wm1, const float* __restrict__ bm1,
    const float* __restrict__ Wm2, const float* __restrict__ bm2,
    const float* __restrict__ Wm3, const float* __restrict__ bm3,
    const float* __restrict__ g1, const float* __restrict__ b1,
    const float* __restrict__ g2, const float* __restrict__ b2,
    float* __restrict__ out)
{
  const int t = blockIdx.x, tid = threadIdx.x;
  __shared__ float xb[RD_], h1b[RD_], h2b[RD_];
  __shared__ float red[2];
  float acc = ybuf[(size_t)t*RD_ + tid] + bout[tid];
  if (mask[t] == 0) acc = 0.f;
  float r = resf[(size_t)t*RD_ + tid] + acc;

  float mean = bsum128(r, red, tid) * (1.f/RD_);
  float d = r - mean;
  float var = bsum128(d*d, red, tid) * (1.f/RD_);
  float xn = d * rsqrtf(var + 1e-5f) * g1[tid] + b1[tid];
  xb[tid] = xn;
  __syncthreads();

  float a1 = bm1[tid];
  {
    const float4* w4 = (const float4*)(Wm1 + (size_t)tid*RD_);
    #pragma unroll
    for (int c = 0; c < RD_/4; ++c) { float4 a = w4[c]; a1 += a.x*xb[4*c]+a.y*xb[4*c+1]+a.z*xb[4*c+2]+a.w*xb[4*c+3]; }
  }
  a1 = fmaxf(a1, 0.f);
  h1b[tid] = a1;
  __syncthreads();

  float a2 = bm2[tid];
  {
    const float4* w4 = (const float4*)(Wm2 + (size_t)tid*RD_);
    #pragma unroll
    for (int c = 0; c < RD_/4; ++c) { float4 a = w4[c]; a2 += a.x*h1b[4*c]+a.y*h1b[4*c+1]+a.z*h1b[4*c+2]+a.w*h1b[4*c+3]; }
  }
  a2 = fmaxf(a2, 0.f);
  h2b[tid] = a2;
  __syncthreads();

  float a3 = bm3[tid];
  {
    const float4* w4 = (const float4*)(Wm3 + (size_t)tid*RD_);
    #pragma unroll
    for (int c = 0; c < RD_/4; ++c) { float4 a = w4[c]; a3 += a.x*h2b[4*c]+a.y*h2b[4*c+1]+a.z*h2b[4*c+2]+a.w*h2b[4*c+3]; }
  }
  float r2 = xn + a3;
  float mean2 = bsum128(r2, red, tid) * (1.f/RD_);
  float d2 = r2 - mean2;
  float var2 = bsum128(d2*d2, red, tid) * (1.f/RD_);
  out[(size_t)t*RD_ + tid] = d2 * rsqrtf(var2 + 1e-5f) * g2[tid] + b2[tid];
}

// ---------------------------------------------------------------------------
extern "C" void kernel_launch(void* const* d_in, const int* in_sizes, int n_in,
                              void* d_out, int out_size, void* d_ws, size_t ws_size,
                              hipStream_t stream) {
  (void)in_sizes; (void)n_in; (void)out_size; (void)ws_size;
  const float* R     = (const float*)d_in[0];
  const float* coord = (const float*)d_in[1];
  const float* resf  = (const float*)d_in[2];
  const float* pair  = (const float*)d_in[3];
  const int*   mask  = (const int*)  d_in[4];
  const float* Wq    = (const float*)d_in[5];
  const float* Wk    = (const float*)d_in[6];
  const float* Wv    = (const float*)d_in[7];
  const float* Wpb   = (const float*)d_in[8];
  const float* spc   = (const float*)d_in[9];
  const float* Wqp   = (const float*)d_in[10];
  const float* Wkp   = (const float*)d_in[11];
  const float* Wvp   = (const float*)d_in[12];
  const float* Wout  = (const float*)d_in[13];
  const float* bout  = (const float*)d_in[14];
  const float* Wm1   = (const float*)d_in[15];
  const float* bm1   = (const float*)d_in[16];
  const float* Wm2   = (const float*)d_in[17];
  const float* bm2   = (const float*)d_in[18];
  const float* Wm3   = (const float*)d_in[19];
  const float* bm3   = (const float*)d_in[20];
  const float* g1    = (const float*)d_in[21];
  const float* b1    = (const float*)d_in[22];
  const float* g2    = (const float*)d_in[23];
  const float* b2    = (const float*)d_in[24];

  float* ws   = (float*)d_ws;
  float* proj = ws;                               // NL*2016
  float* qt   = proj + (size_t)NL_*POUT_;         // 24*512*64
  float* kt   = qt   + (size_t)N_*H_*L_*64;
  float* vpg  = kt   + (size_t)N_*H_*L_*64;       // NL*288
  float* lgal = vpg  + (size_t)NL_*288;           // 24*512*512 (logits -> alpha)
  float* feat = lgal + (size_t)N_*H_*L_*L_;       // NL*1824
  float* ybuf = feat + (size_t)NL_*FEAT_;         // NL*128

  k_proj_gemm<<<dim3(NL_/8, 16), 256, 0, stream>>>(resf, Wq, Wk, Wv, Wqp, Wkp, Wvp, proj);
  k_rot<<<NL_, 64, 0, stream>>>(R, coord, spc, proj, qt, kt, vpg);
  k_lgns<<<dim3(L_/64, L_/64, N_*H_), 256, 0, stream>>>(qt, kt, lgal);
  k_soft<<<NL_, 256, 0, stream>>>(pair, mask, Wpb, lgal);
  k_aggr<<<NL_, 384, 0, stream>>>(pair, proj, vpg, lgal, R, coord, feat);
  k_y_gemm<<<NL_/4, 256, 0, stream>>>(feat, Wout, ybuf);
  k_mlp<<<NL_, 128, 0, stream>>>(resf, mask, ybuf, bout, Wm1, bm1, Wm2, bm2, Wm3, bm3,
                                 g1, b1, g2, b2, (float*)d_out);
}

// Round 3
// 313.122 us; speedup vs baseline: 2.6907x; 1.0143x over previous
//
#include <hip/hip_runtime.h>
#include <hip/hip_bf16.h>

#define N_ 2
#define L_ 512
#define RD_ 128
#define PD_ 64
#define H_ 12
#define NL_ (N_*L_)
#define POUT_ 2016          /* 3*384 + 3*288 */
#define FEAT_ 1824
#define INF_ 100000.0f
#define ISQD_ 0.17677669529663687f   /* 1/sqrt(32) */
#define ISQ3_ 0.5773502691896258f    /* sqrt(1/3) */
#define LGS_ 516            /* alpha row stride in LDS */
#define PTS2_ 66            /* pair tile row stride in LDS */

// ---------------------------------------------------------------------------
// K1: projection GEMM. proj[token][2016] = resf @ [Wq|Wk|Wv|Wqp|Wkp|Wvp]^T
// ---------------------------------------------------------------------------
__global__ __launch_bounds__(256) void k_proj_gemm(
    const float* __restrict__ resf,
    const float* __restrict__ Wq, const float* __restrict__ Wk, const float* __restrict__ Wv,
    const float* __restrict__ Wqp, const float* __restrict__ Wkp, const float* __restrict__ Wvp,
    float* __restrict__ proj)
{
  const int rb = blockIdx.x * 8;
  const int ob = blockIdx.y * 128;
  const int tid = threadIdx.x;
  __shared__ float xt[8*132];
  __shared__ float wt[128*132];
  {
    int r = tid >> 5, kq = (tid & 31) * 4;
    float4 v = *(const float4*)(resf + (size_t)(rb + r)*RD_ + kq);
    xt[r*132+kq]=v.x; xt[r*132+kq+1]=v.y; xt[r*132+kq+2]=v.z; xt[r*132+kq+3]=v.w;
  }
  for (int m = 0; m < 16; ++m) {
    int idx = m*256 + tid;
    int r = idx >> 5, kq = (idx & 31) * 4;
    int o = ob + r;
    float4 v;
    if (o < 384)        v = *(const float4*)(Wq  + (size_t)o*RD_ + kq);
    else if (o < 768)   v = *(const float4*)(Wk  + (size_t)(o-384)*RD_ + kq);
    else if (o < 1152)  v = *(const float4*)(Wv  + (size_t)(o-768)*RD_ + kq);
    else if (o < 1440)  v = *(const float4*)(Wqp + (size_t)(o-1152)*RD_ + kq);
    else if (o < 1728)  v = *(const float4*)(Wkp + (size_t)(o-1440)*RD_ + kq);
    else if (o < POUT_) v = *(const float4*)(Wvp + (size_t)(o-1728)*RD_ + kq);
    else                v = make_float4(0.f,0.f,0.f,0.f);
    wt[r*132+kq]=v.x; wt[r*132+kq+1]=v.y; wt[r*132+kq+2]=v.z; wt[r*132+kq+3]=v.w;
  }
  __syncthreads();
  const int tt = tid & 7, g = tid >> 3;
  float acc0=0.f, acc1=0.f, acc2=0.f, acc3=0.f;
  #pragma unroll 4
  for (int k2 = 0; k2 < RD_; ++k2) {
    float xv = xt[tt*132 + k2];
    acc0 += xv * wt[(g     )*132 + k2];
    acc1 += xv * wt[(g + 32)*132 + k2];
    acc2 += xv * wt[(g + 64)*132 + k2];
    acc3 += xv * wt[(g + 96)*132 + k2];
  }
  float* dst = proj + (size_t)(rb + tt)*POUT_ + ob;
  if (ob + g      < POUT_) dst[g]      = acc0;
  if (ob + g + 32 < POUT_) dst[g+32]   = acc1;
  if (ob + g + 64 < POUT_) dst[g+64]   = acc2;
  if (ob + g + 96 < POUT_) dst[g+96]   = acc3;
}

// ---------------------------------------------------------------------------
// K2: per-token rotate + build Q~/K~ (58-dim augmented, padded to 64)
// ---------------------------------------------------------------------------
__global__ __launch_bounds__(64) void k_rot(
    const float* __restrict__ R, const float* __restrict__ coord,
    const float* __restrict__ spc, const float* __restrict__ proj,
    float* __restrict__ qt, float* __restrict__ kt, float* __restrict__ vpg)
{
  const int t = blockIdx.x;
  const int n = t / L_, i = t % L_;
  const int tid = threadIdx.x;
  __shared__ float prow[POUT_];
  __shared__ float qpl[288], kpl[288], vpl[288];
  __shared__ float qqs[H_], kks[H_], coefs[H_];
  for (int m = tid; m < POUT_/4; m += 64)
    ((float4*)prow)[m] = *((const float4*)(proj + (size_t)t*POUT_) + m);
  if (tid < H_) coefs[tid] = -log1pf(expf(spc[tid])) * (1.0f/12.0f);
  __syncthreads();
  const float* Rm = R + (size_t)t*9;
  const float r00=Rm[0],r01=Rm[1],r02=Rm[2],r10=Rm[3],r11=Rm[4],r12=Rm[5],r20=Rm[6],r21=Rm[7],r22=Rm[8];
  const float cx = coord[(size_t)t*3], cy = coord[(size_t)t*3+1], cz = coord[(size_t)t*3+2];
  for (int idx = tid; idx < 288; idx += 64) {
    int mat = idx / 96, p = idx % 96;
    const float* s = prow + 1152 + mat*288 + p*3;
    float px=s[0], py=s[1], pz=s[2];
    float gx = r00*px + r01*py + r02*pz + cx;
    float gy = r10*px + r11*py + r12*pz + cy;
    float gz = r20*px + r21*py + r22*pz + cz;
    float* d = (mat==0? qpl : mat==1? kpl : vpl) + p*3;
    d[0]=gx; d[1]=gy; d[2]=gz;
  }
  __syncthreads();
  if (tid < 24) {
    int mat = tid / H_, h = tid % H_;
    const float* s = (mat==0? qpl : kpl) + h*24;
    float acc = 0.f;
    #pragma unroll
    for (int c2 = 0; c2 < 24; ++c2) acc += s[c2]*s[c2];
    (mat==0? qqs : kks)[h] = acc;
  }
  for (int m = tid; m < 72; m += 64)
    ((float4*)(vpg + (size_t)t*288))[m] = ((float4*)vpl)[m];
  __syncthreads();
  for (int idx = tid; idx < 2*H_*64; idx += 64) {
    int which = idx / 768, rem = idx % 768, h = rem >> 6, c = rem & 63;
    float val;
    if (which == 0) {
      if (c < 32)       val = prow[h*32 + c] * ISQD_;
      else if (c < 56)  val = qpl[h*24 + (c-32)] * (-2.0f * coefs[h]);
      else if (c == 56) val = coefs[h] * qqs[h];
      else if (c == 57) val = coefs[h];
      else              val = 0.f;
      qt[((size_t)(n*H_ + h)*L_ + i)*64 + c] = val;
    } else {
      if (c < 32)       val = prow[384 + h*32 + c];
      else if (c < 56)  val = kpl[h*24 + (c-32)];
      else if (c == 56) val = 1.0f;
      else if (c == 57) val = kks[h];
      else              val = 0.f;
      kt[((size_t)(n*H_ + h)*L_ + i)*64 + c] = val;
    }
  }
}

// ---------------------------------------------------------------------------
// K3: logits GEMM (node+spatial): lgal[n][h][i][j] = Qt[i] . Kt[j]
// ---------------------------------------------------------------------------
__global__ __launch_bounds__(256) void k_lgns(
    const float* __restrict__ qt, const float* __restrict__ kt,
    float* __restrict__ lgal)
{
  const int jb = blockIdx.x * 64, ib = blockIdx.y * 64, nh = blockIdx.z;
  const int tid = threadIdx.x;
  __shared__ float qs[64*65], ks[64*65];
  for (int m = 0; m < 4; ++m) {
    int idx = m*256 + tid;
    int r = idx >> 4, kq = (idx & 15) * 4;
    float4 a = *(const float4*)(qt + ((size_t)nh*L_ + ib + r)*64 + kq);
    qs[r*65+kq]=a.x; qs[r*65+kq+1]=a.y; qs[r*65+kq+2]=a.z; qs[r*65+kq+3]=a.w;
    float4 b = *(const float4*)(kt + ((size_t)nh*L_ + jb + r)*64 + kq);
    ks[r*65+kq]=b.x; ks[r*65+kq+1]=b.y; ks[r*65+kq+2]=b.z; ks[r*65+kq+3]=b.w;
  }
  __syncthreads();
  const int tx = tid & 15, ty = tid >> 4;
  const int i0 = ty*4, j0 = tx*4;
  float acc[4][4] = {};
  #pragma unroll 2
  for (int k2 = 0; k2 < 64; ++k2) {
    float qv[4], kv[4];
    #pragma unroll
    for (int d = 0; d < 4; ++d) { qv[d] = qs[(i0+d)*65 + k2]; kv[d] = ks[(j0+d)*65 + k2]; }
    #pragma unroll
    for (int a2 = 0; a2 < 4; ++a2)
      #pragma unroll
      for (int b2 = 0; b2 < 4; ++b2) acc[a2][b2] += qv[a2]*kv[b2];
  }
  #pragma unroll
  for (int a2 = 0; a2 < 4; ++a2) {
    float4 v = make_float4(acc[a2][0], acc[a2][1], acc[a2][2], acc[a2][3]);
    *(float4*)(lgal + ((size_t)nh*L_ + ib + i0 + a2)*L_ + jb + j0) = v;
  }
}

// ---------------------------------------------------------------------------
// K4: fused per (n,i): pair-bias + mask + softmax + feat_pair aggregation.
//   pass 1: stream pair tiles (HBM) -> bias into logits
//   softmax -> alpha (written back to lgal for k_av)
//   pass 2: re-stream pair tiles (L2-hot) -> feat_pair
// ---------------------------------------------------------------------------
__global__ __launch_bounds__(256) void k_soft2(
    const float* __restrict__ pair, const int* __restrict__ mask,
    const float* __restrict__ Wpb, float* __restrict__ lgal,
    float* __restrict__ feat)
{
  const int bi = blockIdx.x, n = bi / L_, i = bi % L_, nL = n*L_;
  const int tid = threadIdx.x;
  __shared__ float lg[H_*LGS_];
  __shared__ float pt[64*PTS2_];
  __shared__ float wpb[H_*64];
  __shared__ float mterm[512];

  for (int m = 0; m < 6; ++m) {
    int idx = m*256 + tid;               // 1536 quads = 12 x 128
    int h = idx >> 7, jq = (idx & 127) * 4;
    *(float4*)(lg + h*LGS_ + jq) =
        *(const float4*)(lgal + ((size_t)(n*H_+h)*L_ + i)*L_ + jq);
  }
  for (int m = tid; m < H_*16; m += 256) ((float4*)wpb)[m] = ((const float4*)Wpb)[m];
  const int mi = mask[bi];
  for (int m = tid; m < 512; m += 256) mterm[m] = (mi && mask[nL + m]) ? 0.f : -INF_;
  __syncthreads();

  // ---- pass 1: bias ----
  for (int jb = 0; jb < 512; jb += 64) {
    for (int m = 0; m < 4; ++m) {
      int idx = m*256 + tid;
      int r = idx >> 4, cq = (idx & 15) * 4;
      float4 v = *(const float4*)(pair + ((size_t)bi*L_ + jb + r)*PD_ + cq);
      float* d = pt + r*PTS2_ + cq;
      d[0]=v.x; d[1]=v.y; d[2]=v.z; d[3]=v.w;
    }
    __syncthreads();
    #pragma unroll
    for (int it = 0; it < 3; ++it) {
      int h = it*4 + (tid >> 6), jj = tid & 63;
      const float* pr = pt + jj*PTS2_;
      const float* wr = wpb + h*64;
      float pl = 0.f;
      #pragma unroll
      for (int c = 0; c < 64; c += 2) {
        float2 pv = *(const float2*)(pr + c);
        float2 wv = *(const float2*)(wr + c);
        pl += pv.x*wv.x + pv.y*wv.y;
      }
      int j = jb + jj;
      lg[h*LGS_ + j] = (lg[h*LGS_ + j] + pl) * ISQ3_ + mterm[j];
    }
    __syncthreads();
  }

  // ---- softmax ----
  {
    const int wid = tid >> 6, lane = tid & 63;
    for (int h = wid; h < H_; h += 4) {
      float mx = -1e30f;
      for (int j = lane; j < 512; j += 64) mx = fmaxf(mx, lg[h*LGS_+j]);
      #pragma unroll
      for (int off = 1; off < 64; off <<= 1) mx = fmaxf(mx, __shfl_xor(mx, off, 64));
      float s = 0.f;
      for (int j = lane; j < 512; j += 64) s += expf(lg[h*LGS_+j]-mx);
      #pragma unroll
      for (int off = 1; off < 64; off <<= 1) s += __shfl_xor(s, off, 64);
      float inv = (mi ? 1.f : 0.f) / s;
      for (int j = lane; j < 512; j += 64) lg[h*LGS_+j] = expf(lg[h*LGS_+j]-mx) * inv;
    }
  }
  __syncthreads();

  // write alpha back (k_av consumes it)
  for (int m = 0; m < 6; ++m) {
    int idx = m*256 + tid;
    int h = idx >> 7, jq = (idx & 127) * 4;
    *(float4*)(lgal + ((size_t)(n*H_+h)*L_ + i)*L_ + jq) = *(float4*)(lg + h*LGS_ + jq);
  }

  // ---- pass 2: feat_pair aggregation (pair tiles L2-hot) ----
  const int h = tid >> 4, cq = (tid & 15) << 2;   // valid when tid < 192
  float4 acc = make_float4(0.f,0.f,0.f,0.f);
  for (int jb = 0; jb < 512; jb += 64) {
    __syncthreads();
    for (int m = 0; m < 4; ++m) {
      int idx = m*256 + tid;
      int r = idx >> 4, c2 = (idx & 15) * 4;
      float4 v = *(const float4*)(pair + ((size_t)bi*L_ + jb + r)*PD_ + c2);
      float* d = pt + r*PTS2_ + c2;
      d[0]=v.x; d[1]=v.y; d[2]=v.z; d[3]=v.w;
    }
    __syncthreads();
    if (tid < 192) {
      const float* arow = lg + h*LGS_ + jb;
      #pragma unroll 4
      for (int jj = 0; jj < 64; ++jj) {
        float a = arow[jj];
        const float* pr = pt + jj*PTS2_ + cq;
        float2 p0 = *(const float2*)pr;
        float2 p1 = *(const float2*)(pr + 2);
        acc.x += a*p0.x; acc.y += a*p0.y; acc.z += a*p1.x; acc.w += a*p1.y;
      }
    }
  }
  if (tid < 192) *(float4*)(feat + (size_t)bi*FEAT_ + h*64 + cq) = acc;
}

// ---------------------------------------------------------------------------
// K5: per (n,h) GEMM: C[i, 0:56] = alpha[i,j] @ [v | vp][j, 0:56]
//   cols 0..31 -> feat_node, cols 32..55 -> global-frame point aggregation
// ---------------------------------------------------------------------------
__global__ __launch_bounds__(256) void k_av(
    const float* __restrict__ lgal, const float* __restrict__ proj,
    const float* __restrict__ vpg,
    float* __restrict__ feat, float* __restrict__ aggr)
{
  const int ib = blockIdx.x * 64;
  const int nh = blockIdx.y;
  const int n = nh / H_, h = nh % H_, nL = n*L_;
  const int tid = threadIdx.x;
  __shared__ float as[64*65];
  __shared__ float bs[64*60];
  const int tx = tid & 15, ty = tid >> 4;
  const int i0 = ty*4, c0 = tx*4;
  float acc[4][4] = {};
  for (int jb = 0; jb < 512; jb += 64) {
    for (int m = 0; m < 4; ++m) {
      int idx = m*256 + tid;
      int r = idx >> 4, jq = (idx & 15) * 4;
      float4 a = *(const float4*)(lgal + ((size_t)nh*L_ + ib + r)*L_ + jb + jq);
      as[r*65+jq]=a.x; as[r*65+jq+1]=a.y; as[r*65+jq+2]=a.z; as[r*65+jq+3]=a.w;
    }
    for (int m = 0; m < 4; ++m) {
      int idx = m*256 + tid;
      int j = idx >> 4, qq = idx & 15;
      if (qq < 14) {
        float4 v;
        if (qq < 8) v = *(const float4*)(proj + (size_t)(nL + jb + j)*POUT_ + 768 + h*32 + qq*4);
        else        v = *(const float4*)(vpg  + (size_t)(nL + jb + j)*288  + h*24 + (qq-8)*4);
        float* d = bs + j*60 + qq*4;
        d[0]=v.x; d[1]=v.y; d[2]=v.z; d[3]=v.w;
      }
    }
    __syncthreads();
    #pragma unroll 2
    for (int k2 = 0; k2 < 64; ++k2) {
      float av[4];
      #pragma unroll
      for (int d = 0; d < 4; ++d) av[d] = as[(i0+d)*65 + k2];
      float4 bv = *(const float4*)(bs + k2*60 + c0);
      #pragma unroll
      for (int a2 = 0; a2 < 4; ++a2) {
        acc[a2][0] += av[a2]*bv.x; acc[a2][1] += av[a2]*bv.y;
        acc[a2][2] += av[a2]*bv.z; acc[a2][3] += av[a2]*bv.w;
      }
    }
    __syncthreads();
  }
  if (c0 < 32) {
    #pragma unroll
    for (int a2 = 0; a2 < 4; ++a2)
      *(float4*)(feat + (size_t)(nL + ib + i0 + a2)*FEAT_ + 768 + h*32 + c0) =
          make_float4(acc[a2][0], acc[a2][1], acc[a2][2], acc[a2][3]);
  } else if (c0 < 56) {
    #pragma unroll
    for (int a2 = 0; a2 < 4; ++a2)
      *(float4*)(aggr + (size_t)(nL + ib + i0 + a2)*288 + h*24 + (c0-32)) =
          make_float4(acc[a2][0], acc[a2][1], acc[a2][2], acc[a2][3]);
  }
}

// ---------------------------------------------------------------------------
// K6: per-token point post-process: local frame, dist, dir
// ---------------------------------------------------------------------------
__global__ __launch_bounds__(128) void k_post(
    const float* __restrict__ R, const float* __restrict__ coord,
    const float* __restrict__ aggr, float* __restrict__ feat)
{
  const int t = blockIdx.x, tid = threadIdx.x;
  if (tid >= 96) return;
  const float* Rm = R + (size_t)t*9;
  const float cx = coord[(size_t)t*3], cy = coord[(size_t)t*3+1], cz = coord[(size_t)t*3+2];
  const float* ag = aggr + (size_t)t*288;
  float* fb = feat + (size_t)t*FEAT_;
  float dx = ag[tid*3] - cx, dy = ag[tid*3+1] - cy, dz = ag[tid*3+2] - cz;
  float fx = Rm[0]*dx + Rm[3]*dy + Rm[6]*dz;
  float fy = Rm[1]*dx + Rm[4]*dy + Rm[7]*dz;
  float fz = Rm[2]*dx + Rm[5]*dy + Rm[8]*dz;
  float dist = sqrtf(fx*fx + fy*fy + fz*fz);
  float idn = 1.f/(dist + 1e-4f);
  fb[1152+tid*3]=fx; fb[1152+tid*3+1]=fy; fb[1152+tid*3+2]=fz;
  fb[1440+tid]=dist;
  fb[1536+tid*3]=fx*idn; fb[1536+tid*3+1]=fy*idn; fb[1536+tid*3+2]=fz*idn;
}

// ---------------------------------------------------------------------------
// K7: y = feat @ Wout^T
// ---------------------------------------------------------------------------
__global__ __launch_bounds__(256) void k_y_gemm(
    const float* __restrict__ feat, const float* __restrict__ Wout,
    float* __restrict__ ybuf)
{
  const int rb = blockIdx.x * 4;
  const int tid = threadIdx.x;
  __shared__ float wt[128*100];
  __shared__ float ft[4*100];
  const int tt = tid & 3, g = tid >> 2;
  float acc0 = 0.f, acc1 = 0.f;
  for (int kb = 0; kb < FEAT_; kb += 96) {
    for (int m = 0; m < 12; ++m) {
      int idx = m*256 + tid;
      int r = idx / 24, kq = (idx % 24) * 4;
      float4 v = *(const float4*)(Wout + (size_t)r*FEAT_ + kb + kq);
      wt[r*100+kq]=v.x; wt[r*100+kq+1]=v.y; wt[r*100+kq+2]=v.z; wt[r*100+kq+3]=v.w;
    }
    if (tid < 96) {
      int r = tid / 24, kq = (tid % 24) * 4;
      float4 v = *(const float4*)(feat + (size_t)(rb + r)*FEAT_ + kb + kq);
      ft[r*100+kq]=v.x; ft[r*100+kq+1]=v.y; ft[r*100+kq+2]=v.z; ft[r*100+kq+3]=v.w;
    }
    __syncthreads();
    #pragma unroll 4
    for (int k2 = 0; k2 < 96; ++k2) {
      float fv = ft[tt*100 + k2];
      acc0 += fv * wt[(g     )*100 + k2];
      acc1 += fv * wt[(g + 64)*100 + k2];
    }
    __syncthreads();
  }
  ybuf[(size_t)(rb+tt)*RD_ + g]      = acc0;
  ybuf[(size_t)(rb+tt)*RD_ + g + 64] = acc1;
}

// ---------------------------------------------------------------------------
// K8: per token: bias/mask/residual + LN1 + MLP + LN2
// ---------------------------------------------------------------------------
__device__ __forceinline__ float bsum128(float v, float* red, int tid) {
  #pragma unroll
  for (int off = 1; off < 64; off <<= 1) v += __shfl_xor(v, off, 64);
  __syncthreads();
  if ((tid & 63) == 0) red[tid >> 6] = v;
  __syncthreads();
  return red[0] + red[1];
}

__global__ __launch_bounds__(128) void k_mlp(
    const float* __restrict__ resf, const int* __restrict__ mask,
    const float* __restrict__ ybuf, const float* __restrict__ bout,
    const float* __restrict__ Wm1, const float* __restrict__ bm1,
    const float* __restrict__ Wm2, const float* __restrict__ bm2,
    const float* __restrict__ Wm3, const float* __restrict__ bm3,
    const float* __restrict__ g1, const float* __restrict__ b1,
    const float* __restrict__ g2, const float* __restrict__ b2,
    float* __restrict__ out)
{
  const int t = blockIdx.x, tid = threadIdx.x;
  __shared__ float xb[RD_], h1b[RD_], h2b[RD_];
  __shared__ float red[2];
  float acc = ybuf[(size_t)t*RD_ + tid] + bout[tid];
  if (mask[t] == 0) acc = 0.f;
  float r = resf[(size_t)t*RD_ + tid] + acc;

  float mean = bsum128(r, red, tid) * (1.f/RD_);
  float d = r - mean;
  float var = bsum128(d*d, red, tid) * (1.f/RD_);
  float xn = d * rsqrtf(var + 1e-5f) * g1[tid] + b1[tid];
  xb[tid] = xn;
  __syncthreads();

  float a1 = bm1[tid];
  {
    const float4* w4 = (const float4*)(Wm1 + (size_t)tid*RD_);
    #pragma unroll
    for (int c = 0; c < RD_/4; ++c) { float4 a = w4[c]; a1 += a.x*xb[4*c]+a.y*xb[4*c+1]+a.z*xb[4*c+2]+a.w*xb[4*c+3]; }
  }
  a1 = fmaxf(a1, 0.f);
  h1b[tid] = a1;
  __syncthreads();

  float a2 = bm2[tid];
  {
    const float4* w4 = (const float4*)(Wm2 + (size_t)tid*RD_);
    #pragma unroll
    for (int c = 0; c < RD_/4; ++c) { float4 a = w4[c]; a2 += a.x*h1b[4*c]+a.y*h1b[4*c+1]+a.z*h1b[4*c+2]+a.w*h1b[4*c+3]; }
  }
  a2 = fmaxf(a2, 0.f);
  h2b[tid] = a2;
  __syncthreads();

  float a3 = bm3[tid];
  {
    const float4* w4 = (const float4*)(Wm3 + (size_t)tid*RD_);
    #pragma unroll
    for (int c = 0; c < RD_/4; ++c) { float4 a = w4[c]; a3 += a.x*h2b[4*c]+a.y*h2b[4*c+1]+a.z*h2b[4*c+2]+a.w*h2b[4*c+3]; }
  }
  float r2 = xn + a3;
  float mean2 = bsum128(r2, red, tid) * (1.f/RD_);
  float d2 = r2 - mean2;
  float var2 = bsum128(d2*d2, red, tid) * (1.f/RD_);
  out[(size_t)t*RD_ + tid] = d2 * rsqrtf(var2 + 1e-5f) * g2[tid] + b2[tid];
}

// ---------------------------------------------------------------------------
extern "C" void kernel_launch(void* const* d_in, const int* in_sizes, int n_in,
                              void* d_out, int out_size, void* d_ws, size_t ws_size,
                              hipStream_t stream) {
  (void)in_sizes; (void)n_in; (void)out_size; (void)ws_size;
  const float* R     = (const float*)d_in[0];
  const float* coord = (const float*)d_in[1];
  const float* resf  = (const float*)d_in[2];
  const float* pair  = (const float*)d_in[3];
  const int*   mask  = (const int*)  d_in[4];
  const float* Wq    = (const float*)d_in[5];
  const float* Wk    = (const float*)d_in[6];
  const float* Wv    = (const float*)d_in[7];
  const float* Wpb   = (const float*)d_in[8];
  const float* spc   = (const float*)d_in[9];
  const float* Wqp   = (const float*)d_in[10];
  const float* Wkp   = (const float*)d_in[11];
  const float* Wvp   = (const float*)d_in[12];
  const float* Wout  = (const float*)d_in[13];
  const float* bout  = (const float*)d_in[14];
  const float* Wm1   = (const float*)d_in[15];
  const float* bm1   = (const float*)d_in[16];
  const float* Wm2   = (const float*)d_in[17];
  const float* bm2   = (const float*)d_in[18];
  const float* Wm3   = (const float*)d_in[19];
  const float* bm3   = (const float*)d_in[20];
  const float* g1    = (const float*)d_in[21];
  const float* b1    = (const float*)d_in[22];
  const float* g2    = (const float*)d_in[23];
  const float* b2    = (const float*)d_in[24];

  float* ws   = (float*)d_ws;
  float* proj = ws;                               // NL*2016
  float* qt   = proj + (size_t)NL_*POUT_;         // 24*512*64
  float* kt   = qt   + (size_t)N_*H_*L_*64;
  float* vpg  = kt   + (size_t)N_*H_*L_*64;       // NL*288
  float* lgal = vpg  + (size_t)NL_*288;           // 24*512*512 (logits -> alpha)
  float* feat = lgal + (size_t)N_*H_*L_*L_;       // NL*1824
  float* ybuf = feat + (size_t)NL_*FEAT_;         // NL*128
  float* aggr = ybuf + (size_t)NL_*RD_;           // NL*288

  k_proj_gemm<<<dim3(NL_/8, 16), 256, 0, stream>>>(resf, Wq, Wk, Wv, Wqp, Wkp, Wvp, proj);
  k_rot<<<NL_, 64, 0, stream>>>(R, coord, spc, proj, qt, kt, vpg);
  k_lgns<<<dim3(L_/64, L_/64, N_*H_), 256, 0, stream>>>(qt, kt, lgal);
  k_soft2<<<NL_, 256, 0, stream>>>(pair, mask, Wpb, lgal, feat);
  k_av<<<dim3(L_/64, N_*H_), 256, 0, stream>>>(lgal, proj, vpg, feat, aggr);
  k_post<<<NL_, 128, 0, stream>>>(R, coord, aggr, feat);
  k_y_gemm<<<NL_/4, 256, 0, stream>>>(feat, Wout, ybuf);
  k_mlp<<<NL_, 128, 0, stream>>>(resf, mask, ybuf, bout, Wm1, bm1, Wm2, bm2, Wm3, bm3,
                                 g1, b1, g2, b2, (float*)d_out);
}

// Round 4
// 285.624 us; speedup vs baseline: 2.9497x; 1.0963x over previous
//
#include <hip/hip_runtime.h>
#include <hip/hip_bf16.h>

#define N_ 2
#define L_ 512
#define RD_ 128
#define PD_ 64
#define H_ 12
#define NL_ (N_*L_)
#define POUT_ 2016          /* 3*384 + 3*288 */
#define FEAT_ 1824
#define INF_ 100000.0f
#define ISQD_ 0.17677669529663687f   /* 1/sqrt(32) */
#define ISQ3_ 0.5773502691896258f    /* sqrt(1/3) */
#define LGS_ 516            /* logits/alpha row stride in LDS */

// ---------------------------------------------------------------------------
// K1: projection GEMM. proj[token][2016] = resf @ [Wq|Wk|Wv|Wqp|Wkp|Wvp]^T
// ---------------------------------------------------------------------------
__global__ __launch_bounds__(256) void k_proj_gemm(
    const float* __restrict__ resf,
    const float* __restrict__ Wq, const float* __restrict__ Wk, const float* __restrict__ Wv,
    const float* __restrict__ Wqp, const float* __restrict__ Wkp, const float* __restrict__ Wvp,
    float* __restrict__ proj)
{
  const int rb = blockIdx.x * 8;
  const int ob = blockIdx.y * 128;
  const int tid = threadIdx.x;
  __shared__ float xt[8*132];
  __shared__ float wt[128*132];
  {
    int r = tid >> 5, kq = (tid & 31) * 4;
    float4 v = *(const float4*)(resf + (size_t)(rb + r)*RD_ + kq);
    xt[r*132+kq]=v.x; xt[r*132+kq+1]=v.y; xt[r*132+kq+2]=v.z; xt[r*132+kq+3]=v.w;
  }
  for (int m = 0; m < 16; ++m) {
    int idx = m*256 + tid;
    int r = idx >> 5, kq = (idx & 31) * 4;
    int o = ob + r;
    float4 v;
    if (o < 384)        v = *(const float4*)(Wq  + (size_t)o*RD_ + kq);
    else if (o < 768)   v = *(const float4*)(Wk  + (size_t)(o-384)*RD_ + kq);
    else if (o < 1152)  v = *(const float4*)(Wv  + (size_t)(o-768)*RD_ + kq);
    else if (o < 1440)  v = *(const float4*)(Wqp + (size_t)(o-1152)*RD_ + kq);
    else if (o < 1728)  v = *(const float4*)(Wkp + (size_t)(o-1440)*RD_ + kq);
    else if (o < POUT_) v = *(const float4*)(Wvp + (size_t)(o-1728)*RD_ + kq);
    else                v = make_float4(0.f,0.f,0.f,0.f);
    wt[r*132+kq]=v.x; wt[r*132+kq+1]=v.y; wt[r*132+kq+2]=v.z; wt[r*132+kq+3]=v.w;
  }
  __syncthreads();
  const int tt = tid & 7, g = tid >> 3;
  float acc0=0.f, acc1=0.f, acc2=0.f, acc3=0.f;
  #pragma unroll 4
  for (int k2 = 0; k2 < RD_; ++k2) {
    float xv = xt[tt*132 + k2];
    acc0 += xv * wt[(g     )*132 + k2];
    acc1 += xv * wt[(g + 32)*132 + k2];
    acc2 += xv * wt[(g + 64)*132 + k2];
    acc3 += xv * wt[(g + 96)*132 + k2];
  }
  float* dst = proj + (size_t)(rb + tt)*POUT_ + ob;
  if (ob + g      < POUT_) dst[g]      = acc0;
  if (ob + g + 32 < POUT_) dst[g+32]   = acc1;
  if (ob + g + 64 < POUT_) dst[g+64]   = acc2;
  if (ob + g + 96 < POUT_) dst[g+96]   = acc3;
}

// ---------------------------------------------------------------------------
// K2: per-token rotate + build Q~/K~ (58-dim augmented, padded to 64)
// ---------------------------------------------------------------------------
__global__ __launch_bounds__(64) void k_rot(
    const float* __restrict__ R, const float* __restrict__ coord,
    const float* __restrict__ spc, const float* __restrict__ proj,
    float* __restrict__ qt, float* __restrict__ kt, float* __restrict__ vpg)
{
  const int t = blockIdx.x;
  const int n = t / L_, i = t % L_;
  const int tid = threadIdx.x;
  __shared__ float prow[POUT_];
  __shared__ float qpl[288], kpl[288], vpl[288];
  __shared__ float qqs[H_], kks[H_], coefs[H_];
  for (int m = tid; m < POUT_/4; m += 64)
    ((float4*)prow)[m] = *((const float4*)(proj + (size_t)t*POUT_) + m);
  if (tid < H_) coefs[tid] = -log1pf(expf(spc[tid])) * (1.0f/12.0f);
  __syncthreads();
  const float* Rm = R + (size_t)t*9;
  const float r00=Rm[0],r01=Rm[1],r02=Rm[2],r10=Rm[3],r11=Rm[4],r12=Rm[5],r20=Rm[6],r21=Rm[7],r22=Rm[8];
  const float cx = coord[(size_t)t*3], cy = coord[(size_t)t*3+1], cz = coord[(size_t)t*3+2];
  for (int idx = tid; idx < 288; idx += 64) {
    int mat = idx / 96, p = idx % 96;
    const float* s = prow + 1152 + mat*288 + p*3;
    float px=s[0], py=s[1], pz=s[2];
    float gx = r00*px + r01*py + r02*pz + cx;
    float gy = r10*px + r11*py + r12*pz + cy;
    float gz = r20*px + r21*py + r22*pz + cz;
    float* d = (mat==0? qpl : mat==1? kpl : vpl) + p*3;
    d[0]=gx; d[1]=gy; d[2]=gz;
  }
  __syncthreads();
  if (tid < 24) {
    int mat = tid / H_, h = tid % H_;
    const float* s = (mat==0? qpl : kpl) + h*24;
    float acc = 0.f;
    #pragma unroll
    for (int c2 = 0; c2 < 24; ++c2) acc += s[c2]*s[c2];
    (mat==0? qqs : kks)[h] = acc;
  }
  for (int m = tid; m < 72; m += 64)
    ((float4*)(vpg + (size_t)t*288))[m] = ((float4*)vpl)[m];
  __syncthreads();
  for (int idx = tid; idx < 2*H_*64; idx += 64) {
    int which = idx / 768, rem = idx % 768, h = rem >> 6, c = rem & 63;
    float val;
    if (which == 0) {
      if (c < 32)       val = prow[h*32 + c] * ISQD_;
      else if (c < 56)  val = qpl[h*24 + (c-32)] * (-2.0f * coefs[h]);
      else if (c == 56) val = coefs[h] * qqs[h];
      else if (c == 57) val = coefs[h];
      else              val = 0.f;
      qt[((size_t)(n*H_ + h)*L_ + i)*64 + c] = val;
    } else {
      if (c < 32)       val = prow[384 + h*32 + c];
      else if (c < 56)  val = kpl[h*24 + (c-32)];
      else if (c == 56) val = 1.0f;
      else if (c == 57) val = kks[h];
      else              val = 0.f;
      kt[((size_t)(n*H_ + h)*L_ + i)*64 + c] = val;
    }
  }
}

// ---------------------------------------------------------------------------
// K3: logits GEMM (node+spatial): lgal[n][h][i][j] = Qt[i] . Kt[j]
// ---------------------------------------------------------------------------
__global__ __launch_bounds__(256) void k_lgns(
    const float* __restrict__ qt, const float* __restrict__ kt,
    float* __restrict__ lgal)
{
  const int jb = blockIdx.x * 64, ib = blockIdx.y * 64, nh = blockIdx.z;
  const int tid = threadIdx.x;
  __shared__ float qs[64*65], ks[64*65];
  for (int m = 0; m < 4; ++m) {
    int idx = m*256 + tid;
    int r = idx >> 4, kq = (idx & 15) * 4;
    float4 a = *(const float4*)(qt + ((size_t)nh*L_ + ib + r)*64 + kq);
    qs[r*65+kq]=a.x; qs[r*65+kq+1]=a.y; qs[r*65+kq+2]=a.z; qs[r*65+kq+3]=a.w;
    float4 b = *(const float4*)(kt + ((size_t)nh*L_ + jb + r)*64 + kq);
    ks[r*65+kq]=b.x; ks[r*65+kq+1]=b.y; ks[r*65+kq+2]=b.z; ks[r*65+kq+3]=b.w;
  }
  __syncthreads();
  const int tx = tid & 15, ty = tid >> 4;
  const int i0 = ty*4, j0 = tx*4;
  float acc[4][4] = {};
  #pragma unroll 2
  for (int k2 = 0; k2 < 64; ++k2) {
    float qv[4], kv[4];
    #pragma unroll
    for (int d = 0; d < 4; ++d) { qv[d] = qs[(i0+d)*65 + k2]; kv[d] = ks[(j0+d)*65 + k2]; }
    #pragma unroll
    for (int a2 = 0; a2 < 4; ++a2)
      #pragma unroll
      for (int b2 = 0; b2 < 4; ++b2) acc[a2][b2] += qv[a2]*kv[b2];
  }
  #pragma unroll
  for (int a2 = 0; a2 < 4; ++a2) {
    float4 v = make_float4(acc[a2][0], acc[a2][1], acc[a2][2], acc[a2][3]);
    *(float4*)(lgal + ((size_t)nh*L_ + ib + i0 + a2)*L_ + jb + j0) = v;
  }
}

// ---------------------------------------------------------------------------
// K4: fused per (n,i): pair-bias + mask + softmax + feat_pair aggregation.
// Conflict-free: pass1 tile stride 67 (row-per-lane scalar), pass2 stride 68
// (aligned float4 column slices). Wpb read via wave-uniform scalar loads.
// ---------------------------------------------------------------------------
__global__ __launch_bounds__(256) void k_soft2(
    const float* __restrict__ pair, const int* __restrict__ mask,
    const float* __restrict__ Wpb, float* __restrict__ lgal,
    float* __restrict__ feat)
{
  const int bi = blockIdx.x, n = bi / L_, i = bi % L_, nL = n*L_;
  const int tid = threadIdx.x;
  __shared__ float lg[H_*LGS_];     // 24.8 KB
  __shared__ float pt[32*68];       // 8.7 KB (used at stride 67 or 68)

  for (int m = 0; m < 6; ++m) {
    int idx = m*256 + tid;               // 1536 quads = 12 x 128
    int h = idx >> 7, jq = (idx & 127) * 4;
    *(float4*)(lg + h*LGS_ + jq) =
        *(const float4*)(lgal + ((size_t)(n*H_+h)*L_ + i)*L_ + jq);
  }
  const int mi = mask[bi];
  __syncthreads();

  // ---- pass 1: pair-bias + mask, 16 tiles of 32 j ----
  {
    const int w    = __builtin_amdgcn_readfirstlane(tid >> 6);  // wave id, heads w,w+4,w+8
    const int half = (tid >> 5) & 1;                            // c-half
    const int jj   = tid & 31;
    for (int jb = 0; jb < 512; jb += 32) {
      for (int m = 0; m < 2; ++m) {
        int idx = m*256 + tid;
        int r = idx >> 4, cq = (idx & 15)*4;
        float4 v = *(const float4*)(pair + ((size_t)bi*L_ + jb + r)*PD_ + cq);
        float* d = pt + r*67 + cq;
        d[0]=v.x; d[1]=v.y; d[2]=v.z; d[3]=v.w;
      }
      __syncthreads();
      float a0=0.f, a1=0.f, a2=0.f;
      const float* pr = pt + jj*67 + half*32;
      const float* w0 = Wpb + (w    )*64 + half*32;
      const float* w1 = Wpb + (w + 4)*64 + half*32;
      const float* w2 = Wpb + (w + 8)*64 + half*32;
      #pragma unroll
      for (int c = 0; c < 32; c += 2) {
        float pv0 = pr[c], pv1 = pr[c+1];
        a0 += pv0*w0[c] + pv1*w0[c+1];
        a1 += pv0*w1[c] + pv1*w1[c+1];
        a2 += pv0*w2[c] + pv1*w2[c+1];
      }
      a0 += __shfl_xor(a0, 32, 64);
      a1 += __shfl_xor(a1, 32, 64);
      a2 += __shfl_xor(a2, 32, 64);
      const int j = jb + jj;
      const float mt = (mi && mask[nL + j]) ? 0.f : -INF_;
      if (half == 0) {
        lg[(w    )*LGS_ + j] = (lg[(w    )*LGS_ + j] + a0)*ISQ3_ + mt;
        lg[(w + 4)*LGS_ + j] = (lg[(w + 4)*LGS_ + j] + a1)*ISQ3_ + mt;
        lg[(w + 8)*LGS_ + j] = (lg[(w + 8)*LGS_ + j] + a2)*ISQ3_ + mt;
      }
      __syncthreads();
    }
  }

  // ---- softmax (wave per head, round-robin) ----
  {
    const int wid = tid >> 6, lane = tid & 63;
    for (int h = wid; h < H_; h += 4) {
      float mx = -1e30f;
      for (int j = lane; j < 512; j += 64) mx = fmaxf(mx, lg[h*LGS_+j]);
      #pragma unroll
      for (int off = 1; off < 64; off <<= 1) mx = fmaxf(mx, __shfl_xor(mx, off, 64));
      float s = 0.f;
      for (int j = lane; j < 512; j += 64) s += expf(lg[h*LGS_+j]-mx);
      #pragma unroll
      for (int off = 1; off < 64; off <<= 1) s += __shfl_xor(s, off, 64);
      float inv = (mi ? 1.f : 0.f) / s;
      for (int j = lane; j < 512; j += 64) lg[h*LGS_+j] = expf(lg[h*LGS_+j]-mx) * inv;
    }
  }
  __syncthreads();

  // write alpha back (k_av consumes it)
  for (int m = 0; m < 6; ++m) {
    int idx = m*256 + tid;
    int h = idx >> 7, jq = (idx & 127) * 4;
    *(float4*)(lgal + ((size_t)(n*H_+h)*L_ + i)*L_ + jq) = *(float4*)(lg + h*LGS_ + jq);
  }

  // ---- pass 2: feat_pair aggregation (pair tiles L2-hot), stride 68 ----
  {
    const int h = tid >> 4, cq = (tid & 15) * 4;
    float4 acc = make_float4(0.f,0.f,0.f,0.f);
    for (int jb = 0; jb < 512; jb += 32) {
      __syncthreads();
      for (int m = 0; m < 2; ++m) {
        int idx = m*256 + tid;
        int r = idx >> 4, c2 = (idx & 15)*4;
        float4 v = *(const float4*)(pair + ((size_t)bi*L_ + jb + r)*PD_ + c2);
        *(float4*)(pt + r*68 + c2) = v;
      }
      __syncthreads();
      if (h < H_) {
        const float* arow = lg + h*LGS_ + jb;
        #pragma unroll 4
        for (int jj = 0; jj < 32; ++jj) {
          float a = arow[jj];
          float4 pv = *(const float4*)(pt + jj*68 + cq);
          acc.x += a*pv.x; acc.y += a*pv.y; acc.z += a*pv.z; acc.w += a*pv.w;
        }
      }
    }
    if (h < H_) *(float4*)(feat + (size_t)bi*FEAT_ + h*64 + cq) = acc;
  }
}

// ---------------------------------------------------------------------------
// K5: per (n,h) GEMM: C[i, 0:56] = alpha[i,j] @ [v | vp][j, 0:56]
// ---------------------------------------------------------------------------
__global__ __launch_bounds__(256) void k_av(
    const float* __restrict__ lgal, const float* __restrict__ proj,
    const float* __restrict__ vpg,
    float* __restrict__ feat, float* __restrict__ aggr)
{
  const int ib = blockIdx.x * 64;
  const int nh = blockIdx.y;
  const int n = nh / H_, h = nh % H_, nL = n*L_;
  const int tid = threadIdx.x;
  __shared__ float as[64*65];
  __shared__ float bs[64*60];
  const int tx = tid & 15, ty = tid >> 4;
  const int i0 = ty*4, c0 = tx*4;
  float acc[4][4] = {};
  for (int jb = 0; jb < 512; jb += 64) {
    for (int m = 0; m < 4; ++m) {
      int idx = m*256 + tid;
      int r = idx >> 4, jq = (idx & 15) * 4;
      float4 a = *(const float4*)(lgal + ((size_t)nh*L_ + ib + r)*L_ + jb + jq);
      as[r*65+jq]=a.x; as[r*65+jq+1]=a.y; as[r*65+jq+2]=a.z; as[r*65+jq+3]=a.w;
    }
    for (int m = 0; m < 4; ++m) {
      int idx = m*256 + tid;
      int j = idx >> 4, qq = idx & 15;
      if (qq < 14) {
        float4 v;
        if (qq < 8) v = *(const float4*)(proj + (size_t)(nL + jb + j)*POUT_ + 768 + h*32 + qq*4);
        else        v = *(const float4*)(vpg  + (size_t)(nL + jb + j)*288  + h*24 + (qq-8)*4);
        float* d = bs + j*60 + qq*4;
        d[0]=v.x; d[1]=v.y; d[2]=v.z; d[3]=v.w;
      }
    }
    __syncthreads();
    #pragma unroll 2
    for (int k2 = 0; k2 < 64; ++k2) {
      float av[4];
      #pragma unroll
      for (int d = 0; d < 4; ++d) av[d] = as[(i0+d)*65 + k2];
      float4 bv = *(const float4*)(bs + k2*60 + c0);
      #pragma unroll
      for (int a2 = 0; a2 < 4; ++a2) {
        acc[a2][0] += av[a2]*bv.x; acc[a2][1] += av[a2]*bv.y;
        acc[a2][2] += av[a2]*bv.z; acc[a2][3] += av[a2]*bv.w;
      }
    }
    __syncthreads();
  }
  if (c0 < 32) {
    #pragma unroll
    for (int a2 = 0; a2 < 4; ++a2)
      *(float4*)(feat + (size_t)(nL + ib + i0 + a2)*FEAT_ + 768 + h*32 + c0) =
          make_float4(acc[a2][0], acc[a2][1], acc[a2][2], acc[a2][3]);
  } else if (c0 < 56) {
    #pragma unroll
    for (int a2 = 0; a2 < 4; ++a2)
      *(float4*)(aggr + (size_t)(nL + ib + i0 + a2)*288 + h*24 + (c0-32)) =
          make_float4(acc[a2][0], acc[a2][1], acc[a2][2], acc[a2][3]);
  }
}

// ---------------------------------------------------------------------------
// K6: per-token point post-process: local frame, dist, dir
// ---------------------------------------------------------------------------
__global__ __launch_bounds__(128) void k_post(
    const float* __restrict__ R, const float* __restrict__ coord,
    const float* __restrict__ aggr, float* __restrict__ feat)
{
  const int t = blockIdx.x, tid = threadIdx.x;
  if (tid >= 96) return;
  const float* Rm = R + (size_t)t*9;
  const float cx = coord[(size_t)t*3], cy = coord[(size_t)t*3+1], cz = coord[(size_t)t*3+2];
  const float* ag = aggr + (size_t)t*288;
  float* fb = feat + (size_t)t*FEAT_;
  float dx = ag[tid*3] - cx, dy = ag[tid*3+1] - cy, dz = ag[tid*3+2] - cz;
  float fx = Rm[0]*dx + Rm[3]*dy + Rm[6]*dz;
  float fy = Rm[1]*dx + Rm[4]*dy + Rm[7]*dz;
  float fz = Rm[2]*dx + Rm[5]*dy + Rm[8]*dz;
  float dist = sqrtf(fx*fx + fy*fy + fz*fz);
  float idn = 1.f/(dist + 1e-4f);
  fb[1152+tid*3]=fx; fb[1152+tid*3+1]=fy; fb[1152+tid*3+2]=fz;
  fb[1440+tid]=dist;
  fb[1536+tid*3]=fx*idn; fb[1536+tid*3+1]=fy*idn; fb[1536+tid*3+2]=fz*idn;
}

// ---------------------------------------------------------------------------
// K7: y = feat @ Wout^T.  8 tokens x 64 outputs per block (grid 128x2=256),
// KC=96; Wout traffic cut 8x vs 4-token tiling.
// ---------------------------------------------------------------------------
__global__ __launch_bounds__(256) void k_y_gemm(
    const float* __restrict__ feat, const float* __restrict__ Wout,
    float* __restrict__ ybuf)
{
  const int rb = blockIdx.x * 8;
  const int ob = blockIdx.y * 64;
  const int tid = threadIdx.x;
  __shared__ float wt[96*65];   // [k][out], padded
  __shared__ float ft[96*10];   // [k][tok], padded
  const int o = tid & 63, tg = tid >> 6;     // tokens tg*2, tg*2+1
  float acc0 = 0.f, acc1 = 0.f;
  for (int kb = 0; kb < FEAT_; kb += 96) {
    for (int m = 0; m < 6; ++m) {
      int idx = m*256 + tid;
      int r = idx / 24, cq = (idx % 24) * 4;
      float4 v = *(const float4*)(Wout + (size_t)(ob + r)*FEAT_ + kb + cq);
      wt[(cq  )*65 + r] = v.x;
      wt[(cq+1)*65 + r] = v.y;
      wt[(cq+2)*65 + r] = v.z;
      wt[(cq+3)*65 + r] = v.w;
    }
    if (tid < 192) {
      int t = tid / 24, cq = (tid % 24) * 4;
      float4 v = *(const float4*)(feat + (size_t)(rb + t)*FEAT_ + kb + cq);
      ft[(cq  )*10 + t] = v.x;
      ft[(cq+1)*10 + t] = v.y;
      ft[(cq+2)*10 + t] = v.z;
      ft[(cq+3)*10 + t] = v.w;
    }
    __syncthreads();
    #pragma unroll 4
    for (int k2 = 0; k2 < 96; ++k2) {
      float wv = wt[k2*65 + o];
      float2 fv = *(const float2*)(ft + k2*10 + tg*2);
      acc0 += wv * fv.x;
      acc1 += wv * fv.y;
    }
    __syncthreads();
  }
  ybuf[(size_t)(rb + tg*2    )*RD_ + ob + o] = acc0;
  ybuf[(size_t)(rb + tg*2 + 1)*RD_ + ob + o] = acc1;
}

// ---------------------------------------------------------------------------
// K8: per token: bias/mask/residual + LN1 + MLP + LN2
// ---------------------------------------------------------------------------
__device__ __forceinline__ float bsum128(float v, float* red, int tid) {
  #pragma unroll
  for (int off = 1; off < 64; off <<= 1) v += __shfl_xor(v, off, 64);
  __syncthreads();
  if ((tid & 63) == 0) red[tid >> 6] = v;
  __syncthreads();
  return red[0] + red[1];
}

__global__ __launch_bounds__(128) void k_mlp(
    const float* __restrict__ resf, const int* __restrict__ mask,
    const float* __restrict__ ybuf, const float* __restrict__ bout,
    const float* __restrict__ Wm1, const float* __restrict__ bm1,
    const float* __restrict__ Wm2, const float* __restrict__ bm2,
    const float* __restrict__ Wm3, const float* __restrict__ bm3,
    const float* __restrict__ g1, const float* __restrict__ b1,
    const float* __restrict__ g2, const float* __restrict__ b2,
    float* __restrict__ out)
{
  const int t = blockIdx.x, tid = threadIdx.x;
  __shared__ float xb[RD_], h1b[RD_], h2b[RD_];
  __shared__ float red[2];
  float acc = ybuf[(size_t)t*RD_ + tid] + bout[tid];
  if (mask[t] == 0) acc = 0.f;
  float r = resf[(size_t)t*RD_ + tid] + acc;

  float mean = bsum128(r, red, tid) * (1.f/RD_);
  float d = r - mean;
  float var = bsum128(d*d, red, tid) * (1.f/RD_);
  float xn = d * rsqrtf(var + 1e-5f) * g1[tid] + b1[tid];
  xb[tid] = xn;
  __syncthreads();

  float a1 = bm1[tid];
  {
    const float4* w4 = (const float4*)(Wm1 + (size_t)tid*RD_);
    #pragma unroll
    for (int c = 0; c < RD_/4; ++c) { float4 a = w4[c]; a1 += a.x*xb[4*c]+a.y*xb[4*c+1]+a.z*xb[4*c+2]+a.w*xb[4*c+3]; }
  }
  a1 = fmaxf(a1, 0.f);
  h1b[tid] = a1;
  __syncthreads();

  float a2 = bm2[tid];
  {
    const float4* w4 = (const float4*)(Wm2 + (size_t)tid*RD_);
    #pragma unroll
    for (int c = 0; c < RD_/4; ++c) { float4 a = w4[c]; a2 += a.x*h1b[4*c]+a.y*h1b[4*c+1]+a.z*h1b[4*c+2]+a.w*h1b[4*c+3]; }
  }
  a2 = fmaxf(a2, 0.f);
  h2b[tid] = a2;
  __syncthreads();

  float a3 = bm3[tid];
  {
    const float4* w4 = (const float4*)(Wm3 + (size_t)tid*RD_);
    #pragma unroll
    for (int c = 0; c < RD_/4; ++c) { float4 a = w4[c]; a3 += a.x*h2b[4*c]+a.y*h2b[4*c+1]+a.z*h2b[4*c+2]+a.w*h2b[4*c+3]; }
  }
  float r2 = xn + a3;
  float mean2 = bsum128(r2, red, tid) * (1.f/RD_);
  float d2 = r2 - mean2;
  float var2 = bsum128(d2*d2, red, tid) * (1.f/RD_);
  out[(size_t)t*RD_ + tid] = d2 * rsqrtf(var2 + 1e-5f) * g2[tid] + b2[tid];
}

// ---------------------------------------------------------------------------
extern "C" void kernel_launch(void* const* d_in, const int* in_sizes, int n_in,
                              void* d_out, int out_size, void* d_ws, size_t ws_size,
                              hipStream_t stream) {
  (void)in_sizes; (void)n_in; (void)out_size; (void)ws_size;
  const float* R     = (const float*)d_in[0];
  const float* coord = (const float*)d_in[1];
  const float* resf  = (const float*)d_in[2];
  const float* pair  = (const float*)d_in[3];
  const int*   mask  = (const int*)  d_in[4];
  const float* Wq    = (const float*)d_in[5];
  const float* Wk    = (const float*)d_in[6];
  const float* Wv    = (const float*)d_in[7];
  const float* Wpb   = (const float*)d_in[8];
  const float* spc   = (const float*)d_in[9];
  const float* Wqp   = (const float*)d_in[10];
  const float* Wkp   = (const float*)d_in[11];
  const float* Wvp   = (const float*)d_in[12];
  const float* Wout  = (const float*)d_in[13];
  const float* bout  = (const float*)d_in[14];
  const float* Wm1   = (const float*)d_in[15];
  const float* bm1   = (const float*)d_in[16];
  const float* Wm2   = (const float*)d_in[17];
  const float* bm2   = (const float*)d_in[18];
  const float* Wm3   = (const float*)d_in[19];
  const float* bm3   = (const float*)d_in[20];
  const float* g1    = (const float*)d_in[21];
  const float* b1    = (const float*)d_in[22];
  const float* g2    = (const float*)d_in[23];
  const float* b2    = (const float*)d_in[24];

  float* ws   = (float*)d_ws;
  float* proj = ws;                               // NL*2016
  float* qt   = proj + (size_t)NL_*POUT_;         // 24*512*64
  float* kt   = qt   + (size_t)N_*H_*L_*64;
  float* vpg  = kt   + (size_t)N_*H_*L_*64;       // NL*288
  float* lgal = vpg  + (size_t)NL_*288;           // 24*512*512 (logits -> alpha)
  float* feat = lgal + (size_t)N_*H_*L_*L_;       // NL*1824
  float* ybuf = feat + (size_t)NL_*FEAT_;         // NL*128
  float* aggr = ybuf + (size_t)NL_*RD_;           // NL*288

  k_proj_gemm<<<dim3(NL_/8, 16), 256, 0, stream>>>(resf, Wq, Wk, Wv, Wqp, Wkp, Wvp, proj);
  k_rot<<<NL_, 64, 0, stream>>>(R, coord, spc, proj, qt, kt, vpg);
  k_lgns<<<dim3(L_/64, L_/64, N_*H_), 256, 0, stream>>>(qt, kt, lgal);
  k_soft2<<<NL_, 256, 0, stream>>>(pair, mask, Wpb, lgal, feat);
  k_av<<<dim3(L_/64, N_*H_), 256, 0, stream>>>(lgal, proj, vpg, feat, aggr);
  k_post<<<NL_, 128, 0, stream>>>(R, coord, aggr, feat);
  k_y_gemm<<<dim3(NL_/8, 2), 256, 0, stream>>>(feat, Wout, ybuf);
  k_mlp<<<NL_, 128, 0, stream>>>(resf, mask, ybuf, bout, Wm1, bm1, Wm2, bm2, Wm3, bm3,
                                 g1, b1, g2, b2, (float*)d_out);
}